// Round 1
// baseline (934.962 us; speedup 1.0000x reference)
//
#include <hip/hip_runtime.h>
#include <cstdint>
#include <cstddef>

#define BB   4
#define CIN  64
#define VV   50000
#define COUT 128
#define KK   7
#define NV   32

// ---------------------------------------------------------------------------
// Kernel T: transpose x[B][C][V] -> xt[B][V][C] so the per-vertex gather of a
// full channel column becomes one contiguous 256B read.
// ---------------------------------------------------------------------------
__global__ __launch_bounds__(256) void transpose_k(const float* __restrict__ x,
                                                   float* __restrict__ xt) {
    __shared__ float tile[64][65];  // +1 pad: conflict-free transposed reads
    int b    = blockIdx.y;
    int v0   = blockIdx.x * 64;
    int lane = threadIdx.x & 63;
    int row  = threadIdx.x >> 6;  // 0..3
#pragma unroll
    for (int i = 0; i < 16; i++) {
        int c = row + 4 * i;
        int v = v0 + lane;
        float val = 0.f;
        if (v < VV) val = x[((size_t)b * CIN + c) * VV + v];
        tile[c][lane] = val;
    }
    __syncthreads();
#pragma unroll
    for (int i = 0; i < 16; i++) {
        int v = v0 + row + 4 * i;
        if (v < VV) xt[((size_t)b * VV + v) * CIN + lane] = tile[lane][row + 4 * i];
    }
}

// ---------------------------------------------------------------------------
// Kernel P: pack W[o][c][7] -> Wp[o][c][8] (k padded with 0) for aligned
// float4 loads in the GEMM phase.
// ---------------------------------------------------------------------------
__global__ __launch_bounds__(256) void pack_w_k(const float* __restrict__ W,
                                                float* __restrict__ Wp) {
    int i = blockIdx.x * 256 + threadIdx.x;  // over COUT*CIN = 8192 rows
    if (i < COUT * CIN) {
        const float* src = W + (size_t)i * 7;
        float4 a, b;
        a.x = src[0]; a.y = src[1]; a.z = src[2]; a.w = src[3];
        b.x = src[4]; b.y = src[5]; b.z = src[6]; b.w = 0.f;
        float4* dst = (float4*)(Wp + (size_t)i * 8);
        dst[0] = a;
        dst[1] = b;
    }
}

// ---------------------------------------------------------------------------
// Kernel M: per block: batch b, 32-vertex tile.
//  Phase 1: gather f0..f3 (coalesced via xt), compute 7 symmetric features
//           per (v,c) into LDS G[32][512] (k padded to 8).
//  Phase 2: thread = (o-pair, v-octet); 7-FMA dot per (o,c,v) with W via
//           float4 global loads and G via broadcast ds_read_b128.
// ---------------------------------------------------------------------------
__global__ __launch_bounds__(256) void mesh_k(
        const float* __restrict__ x, const float* __restrict__ xt,
        const void* __restrict__ Gi, const float* __restrict__ Wp,
        const float* __restrict__ Wraw, const float* __restrict__ bias,
        float* __restrict__ out, int use_xt, int use_wp) {
    __shared__ float Gl[NV][CIN * 8];  // 64 KB

    int b   = blockIdx.y;
    int v0  = blockIdx.x * NV;
    int t   = threadIdx.x;
    int lc  = t & 63;   // channel lane
    int grp = t >> 6;   // 0..3

    // Gi dtype sniff: int64 (little-endian, values < 2^31 => high dwords 0)
    // vs int32. Uniform across the whole grid; branch is wave-uniform.
    const unsigned* gu = (const unsigned*)Gi;
    bool is64 = ((gu[1] | gu[3] | gu[5] | gu[7]) == 0u);

    // ---- Phase 1: build G in LDS ----
#pragma unroll
    for (int p = 0; p < NV / 4; ++p) {
        int vv = p * 4 + grp;
        int v  = v0 + vv;
        if (v < VV) {
            long long i0, i1, i2, i3;
            size_t gbase = ((size_t)b * VV + v) * 4;
            if (is64) {
                const long long* g8 = (const long long*)Gi + gbase;
                i0 = g8[0]; i1 = g8[1]; i2 = g8[2]; i3 = g8[3];
            } else {
                const int* g4 = (const int*)Gi + gbase;
                i0 = g4[0]; i1 = g4[1]; i2 = g4[2]; i3 = g4[3];
            }
            // clamp (safety: a wrong dtype guess must not fault)
            i0 = i0 < 0 ? 0 : (i0 >= VV ? VV - 1 : i0);
            i1 = i1 < 0 ? 0 : (i1 >= VV ? VV - 1 : i1);
            i2 = i2 < 0 ? 0 : (i2 >= VV ? VV - 1 : i2);
            i3 = i3 < 0 ? 0 : (i3 >= VV ? VV - 1 : i3);

            float f0, f1, f2, f3;
            if (use_xt) {
                const float* base = xt + (size_t)b * VV * CIN + lc;
                f0 = base[(size_t)i0 * CIN];
                f1 = base[(size_t)i1 * CIN];
                f2 = base[(size_t)i2 * CIN];
                f3 = base[(size_t)i3 * CIN];
            } else {
                const float* base = x + ((size_t)b * CIN + lc) * VV;
                f0 = base[i0]; f1 = base[i1]; f2 = base[i2]; f3 = base[i3];
            }

            float s1  = f1 + f2 + f3;
            float p12 = f1 * f2, p13 = f1 * f3, p23 = f2 * f3;
            float g2  = p12 * f3;
            float g3  = p12 + p13 + p23;
            float g4  = f1 * f1 + f2 * f2 + f3 * f3;
            float g5  = fabsf(f1 - f2) + fabsf(f1 - f3) + fabsf(f2 - f3);
            float g6  = f1 * f1 * f1 + f2 * f2 * f2 + f3 * f3 * f3;

            float* gl = &Gl[vv][lc * 8];
            gl[0] = f0; gl[1] = s1; gl[2] = g2; gl[3] = g3;
            gl[4] = g4; gl[5] = g5; gl[6] = g6; gl[7] = 0.f;
        }
    }
    __syncthreads();

    // ---- Phase 2: out[o, v-tile] = W . G + bias ----
    int o0 = (t & 63) * 2;  // o-pair
    int vh = t >> 6;        // v-octet 0..3

    float acc0[8], acc1[8];
    float bb0 = bias[o0], bb1 = bias[o0 + 1];
#pragma unroll
    for (int i = 0; i < 8; i++) { acc0[i] = bb0; acc1[i] = bb1; }

    for (int c = 0; c < CIN; ++c) {
        float4 w0a, w0b, w1a, w1b;
        if (use_wp) {
            const float4* p0 = (const float4*)(Wp + ((size_t)o0 * CIN + c) * 8);
            const float4* p1 = (const float4*)(Wp + ((size_t)(o0 + 1) * CIN + c) * 8);
            w0a = p0[0]; w0b = p0[1];
            w1a = p1[0]; w1b = p1[1];
        } else {
            const float* p0 = Wraw + ((size_t)o0 * CIN + c) * 7;
            const float* p1 = Wraw + ((size_t)(o0 + 1) * CIN + c) * 7;
            w0a = make_float4(p0[0], p0[1], p0[2], p0[3]);
            w0b = make_float4(p0[4], p0[5], p0[6], 0.f);
            w1a = make_float4(p1[0], p1[1], p1[2], p1[3]);
            w1b = make_float4(p1[4], p1[5], p1[6], 0.f);
        }
#pragma unroll
        for (int v8 = 0; v8 < 8; ++v8) {
            const float4* g4p = (const float4*)&Gl[vh * 8 + v8][c * 8];
            float4 ga = g4p[0], gb = g4p[1];
            acc0[v8] += w0a.x * ga.x + w0a.y * ga.y + w0a.z * ga.z + w0a.w * ga.w
                      + w0b.x * gb.x + w0b.y * gb.y + w0b.z * gb.z;
            acc1[v8] += w1a.x * ga.x + w1a.y * ga.y + w1a.z * ga.z + w1a.w * ga.w
                      + w1b.x * gb.x + w1b.y * gb.y + w1b.z * gb.z;
        }
    }

    // ---- Store (float4, V % 4 == 0 so vector stores stay aligned) ----
    int vbase = v0 + vh * 8;
    float* po = out + ((size_t)b * COUT + o0) * VV + vbase;
    float* p1 = out + ((size_t)b * COUT + o0 + 1) * VV + vbase;
#pragma unroll
    for (int q = 0; q < 2; q++) {
        int v = vbase + q * 4;
        if (v + 3 < VV) {
            *(float4*)(po + q * 4) =
                make_float4(acc0[q * 4], acc0[q * 4 + 1], acc0[q * 4 + 2], acc0[q * 4 + 3]);
            *(float4*)(p1 + q * 4) =
                make_float4(acc1[q * 4], acc1[q * 4 + 1], acc1[q * 4 + 2], acc1[q * 4 + 3]);
        } else {
            for (int i = 0; i < 4; i++)
                if (v + i < VV) { po[q * 4 + i] = acc0[q * 4 + i]; p1[q * 4 + i] = acc1[q * 4 + i]; }
        }
    }
}

// ---------------------------------------------------------------------------
extern "C" void kernel_launch(void* const* d_in, const int* in_sizes, int n_in,
                              void* d_out, int out_size, void* d_ws, size_t ws_size,
                              hipStream_t stream) {
    const float* x    = (const float*)d_in[0];
    const void*  Gi   = d_in[1];
    const float* W    = (const float*)d_in[2];
    const float* bias = (const float*)d_in[3];
    float* out        = (float*)d_out;

    size_t xt_bytes = (size_t)BB * VV * CIN * sizeof(float);   // 51.2 MB
    size_t wp_bytes = (size_t)COUT * CIN * 8 * sizeof(float);  // 256 KB

    int use_xt = 0, use_wp = 0;
    float* xt = nullptr;
    float* Wp = nullptr;
    if (ws_size >= xt_bytes + wp_bytes) {
        xt = (float*)d_ws;
        Wp = (float*)((char*)d_ws + xt_bytes);
        use_xt = 1; use_wp = 1;
    } else if (ws_size >= wp_bytes) {
        Wp = (float*)d_ws;
        use_wp = 1;
    }

    if (use_xt) {
        dim3 g((VV + 63) / 64, BB);
        transpose_k<<<g, 256, 0, stream>>>(x, xt);
    }
    if (use_wp) {
        pack_w_k<<<(COUT * CIN + 255) / 256, 256, 0, stream>>>(W, Wp);
    }
    dim3 gm((VV + NV - 1) / NV, BB);
    mesh_k<<<gm, 256, 0, stream>>>(x, xt, Gi, Wp, W, bias, out, use_xt, use_wp);
}